// Round 1
// baseline (357.103 us; speedup 1.0000x reference)
//
#include <hip/hip_runtime.h>

// Output layout (floats): pan [4,1,1024,1024] | lrms [4,4,256,256] | ms_up [4,4,1024,1024]
#define PAN_SZ  4194304
#define LRMS_OFF 4194304
#define MS_OFF  5242880

// ---------------------------------------------------------------------------
// K_eff[c][44][44] = (1/16) * sum_{di,dj in 0..3} mtf[c][p-di][q-dj]  (valid)
// i.e. the 41x41 MTF kernel convolved with a 4x4 box (folds avg-pool into conv)
__global__ __launch_bounds__(256) void build_keff_kernel(
    const float* __restrict__ mtf, float* __restrict__ keff) {
  int e = blockIdx.x * 256 + threadIdx.x;
  if (e >= 4 * 44 * 44) return;
  int c = e / 1936;
  int rem = e - c * 1936;
  int p = rem / 44;
  int q = rem - p * 44;
  float s = 0.f;
  for (int di = 0; di < 4; ++di) {
    int u = p - di;
    if (u < 0 || u > 40) continue;
    for (int dj = 0; dj < 4; ++dj) {
      int v = q - dj;
      if (v < 0 || v > 40) continue;
      s += mtf[(c * 41 + u) * 41 + v];
    }
  }
  keff[e] = s * 0.0625f;
}

// ---------------------------------------------------------------------------
// pan[b][hw] = sum_c x[b][c][hw] * w[c], vectorized float4
__global__ __launch_bounds__(256) void pan_kernel(
    const float* __restrict__ x, const float* __restrict__ w,
    float* __restrict__ pan) {
  int g = blockIdx.x * 256 + threadIdx.x;     // float4 index, 0..1048575
  int b = g >> 18;                            // 262144 float4 per image plane
  int e = g & 262143;
  const float4* x4 = (const float4*)x;
  float w0 = w[0], w1 = w[1], w2 = w[2], w3 = w[3];
  float4 a0 = x4[(size_t)(b * 4 + 0) * 262144 + e];
  float4 a1 = x4[(size_t)(b * 4 + 1) * 262144 + e];
  float4 a2 = x4[(size_t)(b * 4 + 2) * 262144 + e];
  float4 a3 = x4[(size_t)(b * 4 + 3) * 262144 + e];
  float4 o;
  o.x = a0.x * w0 + a1.x * w1 + a2.x * w2 + a3.x * w3;
  o.y = a0.y * w0 + a1.y * w1 + a2.y * w2 + a3.y * w3;
  o.z = a0.z * w0 + a1.z * w1 + a2.z * w2 + a3.z * w3;
  o.w = a0.w * w0 + a1.w * w1 + a2.w * w2 + a3.w * w3;
  ((float4*)pan)[g] = o;
}

// ---------------------------------------------------------------------------
// lrms: stride-4 44x44 depthwise conv over edge-padded x.
// Block: (blockIdx.x = group of 4 output rows, blockIdx.y = image b*4+c).
// 256 threads: r = tid>>6 (output row in group), c = tid&63 (4 output cols each).
// One padded input row (1064 floats) staged per iteration in phase-deinterleaved
// LDS layout P[q%4][col/4] so per-lane reads are contiguous ds_read_b128.
__global__ __launch_bounds__(256) void lrms_kernel(
    const float* __restrict__ x, const float* __restrict__ keff,
    float* __restrict__ lrms) {
  __shared__ __align__(16) float Ksh[1936];     // K_eff for this channel, 44x44
  __shared__ __align__(16) float P[4][272];     // phase-deinterleaved row (266 used)

  int img = blockIdx.y;           // 0..15 = b*4 + ch
  int rg  = blockIdx.x;           // 0..63
  int ch  = img & 3;
  int tid = threadIdx.x;

  for (int e = tid; e < 1936; e += 256) Ksh[e] = keff[ch * 1936 + e];

  int c = tid & 63;
  int r = tid >> 6;
  int i0 = rg * 4;
  const float* ximg = x + (size_t)img * 1048576;

  float acc0 = 0.f, acc1 = 0.f, acc2 = 0.f, acc3 = 0.f;
  __syncthreads();

  for (int t = 0; t < 56; ++t) {
    // stage padded input row Yin = 4*i0 + t  (edge clamp)
    int gy = 4 * i0 + t - 20;
    gy = gy < 0 ? 0 : (gy > 1023 ? 1023 : gy);
    const float* xrow = ximg + (size_t)gy * 1024;
    for (int cl = tid; cl < 1064; cl += 256) {
      int gx = cl - 20;
      gx = gx < 0 ? 0 : (gx > 1023 ? 1023 : gx);
      P[cl & 3][cl >> 2] = xrow[gx];
    }
    __syncthreads();

    int p = t - 4 * r;            // kernel row for this wave's output row
    if (p >= 0 && p < 44) {
      p = __builtin_amdgcn_readfirstlane(p);   // wave-uniform
      float v[4][16];
      #pragma unroll
      for (int rq = 0; rq < 4; ++rq) {
        const float4* ph = (const float4*)(&P[rq][0]);
        #pragma unroll
        for (int j = 0; j < 4; ++j) {
          float4 t4 = ph[c + j];
          v[rq][4 * j + 0] = t4.x;
          v[rq][4 * j + 1] = t4.y;
          v[rq][4 * j + 2] = t4.z;
          v[rq][4 * j + 3] = t4.w;
        }
      }
      const float4* K4 = (const float4*)(&Ksh[p * 44]);
      #pragma unroll
      for (int a = 0; a < 11; ++a) {
        float4 kv = K4[a];        // taps q = 4a+0..3 (broadcast read)
        acc0 += v[0][a] * kv.x + v[1][a] * kv.y + v[2][a] * kv.z + v[3][a] * kv.w;
        acc1 += v[0][a+1] * kv.x + v[1][a+1] * kv.y + v[2][a+1] * kv.z + v[3][a+1] * kv.w;
        acc2 += v[0][a+2] * kv.x + v[1][a+2] * kv.y + v[2][a+2] * kv.z + v[3][a+2] * kv.w;
        acc3 += v[0][a+3] * kv.x + v[1][a+3] * kv.y + v[2][a+3] * kv.z + v[3][a+3] * kv.w;
      }
    }
    __syncthreads();
  }

  float4 res = make_float4(acc0, acc1, acc2, acc3);
  ((float4*)lrms)[(size_t)(img * 256 + i0 + r) * 64 + c] = res;
}

// ---------------------------------------------------------------------------
// Fused double x2 polyphase upsample (interp23tap, 2 stages), circular wrap.
// Stage A (phase 1): out[2j+1]=cur[j]; out[2j]   = sum_s k2[s]*cur[j+s-6]
// Stage B (phase 0): out[2j]  =cur[j]; out[2j+1] = sum_s k2[s]*cur[j+s-5]
// k2[s] = interp_kernel[2s] (the only nonzero taps), s=0..11.
// Per block: 64x64 output tile of one image, via LDS chain lr->t1->s1->t2->out.
__global__ __launch_bounds__(256) void interp_kernel(
    const float* __restrict__ lrms, const float* __restrict__ ik,
    float* __restrict__ ms) {
  __shared__ float lr[32][33];    // lrms tile, rows/cols base (16*bidx - 8)
  __shared__ float t1[32][44];    // stage A horizontal, 43 cols used
  __shared__ float s1[43][44];    // stage A full, 43x43 used
  __shared__ float t2[43][64];    // stage B horizontal
  __shared__ float k2[12];

  int img = blockIdx.z;
  int bx = blockIdx.x, by = blockIdx.y;   // 16 x 16 tiles of 64x64
  int tid = threadIdx.x;

  if (tid < 12) k2[tid] = ik[2 * tid];

  const float* L = lrms + (size_t)img * 65536;
  int ybase = by * 16 - 8, xbase = bx * 16 - 8;
  for (int e = tid; e < 32 * 32; e += 256) {
    int yy = e >> 5, xx = e & 31;
    int gy = (ybase + yy) & 255;
    int gx = (xbase + xx) & 255;
    lr[yy][xx] = L[gy * 256 + gx];
  }
  __syncthreads();

  // t1[yy][cc]: stage A along W. global col = bx*32 - 5 + cc
  for (int e = tid; e < 32 * 43; e += 256) {
    int yy = e / 43, cc = e - yy * 43;
    float val;
    if ((cc & 1) == 0) {                       // odd global col -> passthrough
      val = lr[yy][(cc >> 1) + 5];
    } else {                                   // even global col -> 12-tap
      int base = (cc - 5) >> 1;                // exact (cc-5 even)
      float s = 0.f;
      #pragma unroll
      for (int t = 0; t < 12; ++t) s += k2[t] * lr[yy][base + 2 + t];
      val = s;
    }
    t1[yy][cc] = val;
  }
  __syncthreads();

  // s1[rr][cc]: stage A along H. global row = by*32 - 5 + rr
  for (int e = tid; e < 43 * 43; e += 256) {
    int rr = e / 43, cc = e - rr * 43;
    float val;
    if ((rr & 1) == 0) {
      val = t1[(rr >> 1) + 5][cc];
    } else {
      int base = (rr - 5) >> 1;
      float s = 0.f;
      #pragma unroll
      for (int t = 0; t < 12; ++t) s += k2[t] * t1[base + 2 + t][cc];
      val = s;
    }
    s1[rr][cc] = val;
  }
  __syncthreads();

  // t2[rr][mm]: stage B along W. global col = bx*64 + mm
  for (int e = tid; e < 43 * 64; e += 256) {
    int rr = e >> 6, mm = e & 63;
    float val;
    if ((mm & 1) == 0) {                       // even global col -> passthrough
      val = s1[rr][(mm >> 1) + 5];
    } else {
      int base = (mm - 1) >> 1;
      float s = 0.f;
      #pragma unroll
      for (int t = 0; t < 12; ++t) s += k2[t] * s1[rr][base + t];
      val = s;
    }
    t2[rr][mm] = val;
  }
  __syncthreads();

  // out[nn][mm]: stage B along H. global row = by*64 + nn
  float* O = ms + (size_t)img * 1048576 + (size_t)(by * 64) * 1024 + bx * 64;
  for (int e = tid; e < 64 * 64; e += 256) {
    int nn = e >> 6, mm = e & 63;
    float val;
    if ((nn & 1) == 0) {
      val = t2[(nn >> 1) + 5][mm];
    } else {
      int base = (nn - 1) >> 1;
      float s = 0.f;
      #pragma unroll
      for (int t = 0; t < 12; ++t) s += k2[t] * t2[base + t][mm];
      val = s;
    }
    O[(size_t)nn * 1024 + mm] = val;
  }
}

// ---------------------------------------------------------------------------
extern "C" void kernel_launch(void* const* d_in, const int* in_sizes, int n_in,
                              void* d_out, int out_size, void* d_ws, size_t ws_size,
                              hipStream_t stream) {
  const float* x   = (const float*)d_in[0];   // [4,4,1024,1024]
  const float* mtf = (const float*)d_in[1];   // [4,41,41]
  const float* ik  = (const float*)d_in[2];   // [23]
  const float* pw  = (const float*)d_in[3];   // [4]
  float* out = (float*)d_out;
  float* keff = (float*)d_ws;                 // 4*44*44 floats = 31 KB

  build_keff_kernel<<<31, 256, 0, stream>>>(mtf, keff);
  pan_kernel<<<4096, 256, 0, stream>>>(x, pw, out);
  lrms_kernel<<<dim3(64, 16), 256, 0, stream>>>(x, keff, out + LRMS_OFF);
  interp_kernel<<<dim3(16, 16, 16), 256, 0, stream>>>(out + LRMS_OFF, ik, out + MS_OFF);
}

// Round 2
// 323.495 us; speedup vs baseline: 1.1039x; 1.1039x over previous
//
#include <hip/hip_runtime.h>

// Output layout (floats): pan [4,1,1024,1024] | lrms [4,4,256,256] | ms_up [4,4,1024,1024]
#define PAN_SZ  4194304
#define LRMS_OFF 4194304
#define MS_OFF  5242880

// ---------------------------------------------------------------------------
// K_eff[c][44][44] = (1/16) * sum_{di,dj in 0..3} mtf[c][p-di][q-dj]  (valid)
__global__ __launch_bounds__(256) void build_keff_kernel(
    const float* __restrict__ mtf, float* __restrict__ keff) {
  int e = blockIdx.x * 256 + threadIdx.x;
  if (e >= 4 * 44 * 44) return;
  int c = e / 1936;
  int rem = e - c * 1936;
  int p = rem / 44;
  int q = rem - p * 44;
  float s = 0.f;
  for (int di = 0; di < 4; ++di) {
    int u = p - di;
    if (u < 0 || u > 40) continue;
    for (int dj = 0; dj < 4; ++dj) {
      int v = q - dj;
      if (v < 0 || v > 40) continue;
      s += mtf[(c * 41 + u) * 41 + v];
    }
  }
  keff[e] = s * 0.0625f;
}

// ---------------------------------------------------------------------------
__global__ __launch_bounds__(256) void pan_kernel(
    const float* __restrict__ x, const float* __restrict__ w,
    float* __restrict__ pan) {
  int g = blockIdx.x * 256 + threadIdx.x;
  int b = g >> 18;
  int e = g & 262143;
  const float4* x4 = (const float4*)x;
  float w0 = w[0], w1 = w[1], w2 = w[2], w3 = w[3];
  float4 a0 = x4[(size_t)(b * 4 + 0) * 262144 + e];
  float4 a1 = x4[(size_t)(b * 4 + 1) * 262144 + e];
  float4 a2 = x4[(size_t)(b * 4 + 2) * 262144 + e];
  float4 a3 = x4[(size_t)(b * 4 + 3) * 262144 + e];
  float4 o;
  o.x = a0.x * w0 + a1.x * w1 + a2.x * w2 + a3.x * w3;
  o.y = a0.y * w0 + a1.y * w1 + a2.y * w2 + a3.y * w3;
  o.z = a0.z * w0 + a1.z * w1 + a2.z * w2 + a3.z * w3;
  o.w = a0.w * w0 + a1.w * w1 + a2.w * w2 + a3.w * w3;
  ((float4*)pan)[g] = o;
}

// ---------------------------------------------------------------------------
// lrms: stride-4 44x44 depthwise conv over edge-padded x (pool folded into K).
// Block = 256 threads = 4 waves, covers 8 output rows x 256 cols.
// Wave w owns output rows i0+2w, i0+2w+1 (adjacent -> pB = pA-4, v-reuse ~1.9x).
// 4 input rows staged per barrier-pair, double-buffered; loads issued into regs
// BEFORE the compute phase (async split), written to LDS after the barrier.
// LDS layout phase-deinterleaved P[buf][s][phase][col]: unpack = ds_read_b128.
__global__ __launch_bounds__(256) void lrms_kernel(
    const float* __restrict__ x, const float* __restrict__ keff,
    float* __restrict__ lrms) {
  __shared__ __align__(16) float Ksh[1936];          // 44x44 K_eff, this channel
  __shared__ __align__(16) float P[2][4][4][272];    // [buf][row][phase][col]

  int img = blockIdx.y;           // b*4 + ch
  int ch  = img & 3;
  int i0  = blockIdx.x * 8;       // first output row of this block
  int tid = threadIdx.x;
  int w   = tid >> 6;             // wave id (also: staged-row slot)
  int lane = tid & 63;

  for (int e = tid; e < 1936; e += 256) Ksh[e] = keff[ch * 1936 + e];

  const float* ximg = x + (size_t)img * 1048576;
  int gybase = 4 * i0 - 20;

  float accA[4] = {0.f, 0.f, 0.f, 0.f};
  float accB[4] = {0.f, 0.f, 0.f, 0.f};
  float4 r[5];

  // ---- staging helpers (each wave stages one input row per iteration) ----
  auto ld4c = [&](const float* row, int g) -> float4 {
    if ((unsigned)g <= 1020u) return *(const float4*)(row + g);
    float4 v;
    v.x = row[min(max(g + 0, 0), 1023)];
    v.y = row[min(max(g + 1, 0), 1023)];
    v.z = row[min(max(g + 2, 0), 1023)];
    v.w = row[min(max(g + 3, 0), 1023)];
    return v;
  };
  auto stage_load = [&](int it) {
    int gy = gybase + 4 * it + w;
    gy = gy < 0 ? 0 : (gy > 1023 ? 1023 : gy);
    const float* xrow = ximg + (size_t)gy * 1024;
    #pragma unroll
    for (int j = 0; j < 5; ++j) {
      int kk = lane + 64 * j;                 // float4-col 0..265
      if (j < 4 || lane < 10) r[j] = ld4c(xrow, 4 * kk - 20);
    }
  };
  auto stage_write = [&](int buf) {
    float* B = &P[buf][w][0][0];
    #pragma unroll
    for (int j = 0; j < 5; ++j) {
      int kk = lane + 64 * j;
      if (j < 4 || lane < 10) {
        B[0 * 272 + kk] = r[j].x;
        B[1 * 272 + kk] = r[j].y;
        B[2 * 272 + kk] = r[j].z;
        B[3 * 272 + kk] = r[j].w;
      }
    }
  };

  // prologue: stage iteration 0 into buffer 0
  stage_load(0);
  stage_write(0);
  __syncthreads();

  for (int it = 0; it < 18; ++it) {
    int cur = it & 1;
    if (it < 17) stage_load(it + 1);          // issue early; latency hides under compute

    #pragma unroll
    for (int s = 0; s < 4; ++s) {
      int trel = 4 * it + s;
      int pA = trel - 8 * w;                  // kernel row for output i0+2w
      int pB = pA - 4;                        // kernel row for output i0+2w+1
      bool vA = (unsigned)pA < 44u;
      bool vB = (unsigned)pB < 44u;
      if (vA | vB) {
        float v[4][16];
        #pragma unroll
        for (int ph = 0; ph < 4; ++ph) {
          const float4* F = (const float4*)&P[cur][s][ph][0];
          #pragma unroll
          for (int j = 0; j < 4; ++j) {
            float4 t4 = F[lane + j];
            v[ph][4 * j + 0] = t4.x;
            v[ph][4 * j + 1] = t4.y;
            v[ph][4 * j + 2] = t4.z;
            v[ph][4 * j + 3] = t4.w;
          }
        }
        if (vA) {
          const float4* K4 = (const float4*)(&Ksh[pA * 44]);
          #pragma unroll
          for (int a = 0; a < 11; ++a) {
            float4 kv = K4[a];
            #pragma unroll
            for (int j = 0; j < 4; ++j)
              accA[j] += v[0][a + j] * kv.x + v[1][a + j] * kv.y +
                         v[2][a + j] * kv.z + v[3][a + j] * kv.w;
          }
        }
        if (vB) {
          const float4* K4 = (const float4*)(&Ksh[pB * 44]);
          #pragma unroll
          for (int a = 0; a < 11; ++a) {
            float4 kv = K4[a];
            #pragma unroll
            for (int j = 0; j < 4; ++j)
              accB[j] += v[0][a + j] * kv.x + v[1][a + j] * kv.y +
                         v[2][a + j] * kv.z + v[3][a + j] * kv.w;
          }
        }
      }
    }
    __syncthreads();
    if (it < 17) {
      stage_write(cur ^ 1);
      __syncthreads();
    }
  }

  int oyA = i0 + 2 * w;
  ((float4*)lrms)[((size_t)img * 256 + oyA) * 64 + lane] =
      make_float4(accA[0], accA[1], accA[2], accA[3]);
  ((float4*)lrms)[((size_t)img * 256 + oyA + 1) * 64 + lane] =
      make_float4(accB[0], accB[1], accB[2], accB[3]);
}

// ---------------------------------------------------------------------------
// Fused double x2 polyphase upsample (interp23tap, 2 stages), circular wrap.
__global__ __launch_bounds__(256) void interp_kernel(
    const float* __restrict__ lrms, const float* __restrict__ ik,
    float* __restrict__ ms) {
  __shared__ float lr[32][33];
  __shared__ float t1[32][44];
  __shared__ float s1[43][44];
  __shared__ float t2[43][64];
  __shared__ float k2[12];

  int img = blockIdx.z;
  int bx = blockIdx.x, by = blockIdx.y;
  int tid = threadIdx.x;

  if (tid < 12) k2[tid] = ik[2 * tid];

  const float* L = lrms + (size_t)img * 65536;
  int ybase = by * 16 - 8, xbase = bx * 16 - 8;
  for (int e = tid; e < 32 * 32; e += 256) {
    int yy = e >> 5, xx = e & 31;
    int gy = (ybase + yy) & 255;
    int gx = (xbase + xx) & 255;
    lr[yy][xx] = L[gy * 256 + gx];
  }
  __syncthreads();

  for (int e = tid; e < 32 * 43; e += 256) {
    int yy = e / 43, cc = e - yy * 43;
    float val;
    if ((cc & 1) == 0) {
      val = lr[yy][(cc >> 1) + 5];
    } else {
      int base = (cc - 5) >> 1;
      float s = 0.f;
      #pragma unroll
      for (int t = 0; t < 12; ++t) s += k2[t] * lr[yy][base + 2 + t];
      val = s;
    }
    t1[yy][cc] = val;
  }
  __syncthreads();

  for (int e = tid; e < 43 * 43; e += 256) {
    int rr = e / 43, cc = e - rr * 43;
    float val;
    if ((rr & 1) == 0) {
      val = t1[(rr >> 1) + 5][cc];
    } else {
      int base = (rr - 5) >> 1;
      float s = 0.f;
      #pragma unroll
      for (int t = 0; t < 12; ++t) s += k2[t] * t1[base + 2 + t][cc];
      val = s;
    }
    s1[rr][cc] = val;
  }
  __syncthreads();

  for (int e = tid; e < 43 * 64; e += 256) {
    int rr = e >> 6, mm = e & 63;
    float val;
    if ((mm & 1) == 0) {
      val = s1[rr][(mm >> 1) + 5];
    } else {
      int base = (mm - 1) >> 1;
      float s = 0.f;
      #pragma unroll
      for (int t = 0; t < 12; ++t) s += k2[t] * s1[rr][base + t];
      val = s;
    }
    t2[rr][mm] = val;
  }
  __syncthreads();

  float* O = ms + (size_t)img * 1048576 + (size_t)(by * 64) * 1024 + bx * 64;
  for (int e = tid; e < 64 * 64; e += 256) {
    int nn = e >> 6, mm = e & 63;
    float val;
    if ((nn & 1) == 0) {
      val = t2[(nn >> 1) + 5][mm];
    } else {
      int base = (nn - 1) >> 1;
      float s = 0.f;
      #pragma unroll
      for (int t = 0; t < 12; ++t) s += k2[t] * t2[base + t][mm];
      val = s;
    }
    O[(size_t)nn * 1024 + mm] = val;
  }
}

// ---------------------------------------------------------------------------
extern "C" void kernel_launch(void* const* d_in, const int* in_sizes, int n_in,
                              void* d_out, int out_size, void* d_ws, size_t ws_size,
                              hipStream_t stream) {
  const float* x   = (const float*)d_in[0];   // [4,4,1024,1024]
  const float* mtf = (const float*)d_in[1];   // [4,41,41]
  const float* ik  = (const float*)d_in[2];   // [23]
  const float* pw  = (const float*)d_in[3];   // [4]
  float* out = (float*)d_out;
  float* keff = (float*)d_ws;                 // 4*44*44 floats

  build_keff_kernel<<<31, 256, 0, stream>>>(mtf, keff);
  pan_kernel<<<4096, 256, 0, stream>>>(x, pw, out);
  lrms_kernel<<<dim3(32, 16), 256, 0, stream>>>(x, keff, out + LRMS_OFF);
  interp_kernel<<<dim3(16, 16, 16), 256, 0, stream>>>(out + LRMS_OFF, ik, out + MS_OFF);
}